// Round 9
// baseline (321.531 us; speedup 1.0000x reference)
//
#include <hip/hip_runtime.h>

// GCN 3-layer forward on MI355X.
// Key identity: segment_sum(M) @ W == segment_sum(M @ W), so each layer's
// matmul runs BEFORE aggregation. Layer 1's mm depends only on inputs ->
// fused into the CSR-build count dispatch with ROLE-STRIPED blocks (every
// 3rd block is an mm tile) so both populations are co-resident and the
// VALU-bound mm hides under the ~75us memory-side atomic RMW floor.
// Pipeline:
//   [mm1 ||| count+slot]  striped heterogeneous dispatch
//   scan -> row_ptr, norms
//   [scatter || convert] col placement + xb1 = bf16(ns*T1)
//   agg128 (bf16 gather-sum) -> agg1
//   mm128_l2: X' = relu(nd*agg1+b1) @ W2, out bf16(ns*.) -> xb2
//   agg128 -> agg2
//   mm40_l3: X'' = ns*relu(nd*agg2+b2) @ W3 -> y fp32
//   agg40: nd * sum y + b3 -> out

#define SCAN_CHUNK 4096

__device__ __forceinline__ ushort f2bf(float f) {
    unsigned u = __float_as_uint(f);
    unsigned r = (u + 0x7fffu + ((u >> 16) & 1u)) >> 16;  // RN-even
    return (ushort)r;
}
__device__ __forceinline__ void unpack2(unsigned w, float& lo, float& hi) {
    lo = __uint_as_float(w << 16);
    hi = __uint_as_float(w & 0xffff0000u);
}

// Striped heterogeneous dispatch: among the first 3*mb blocks, those with
// g%3==0 compute T1 = x@W1 tiles (mi = g/3); all other blocks run the CSR
// count+slot atomic pass with consecutive edge ranges. eb ~= 2*mb keeps the
// stripe dense. __launch_bounds__(256,8): 8 blocks/CU so the count blocks
// keep 32 waves/CU of atomics in flight (VGPR 52 < 64 cap).
__global__ __launch_bounds__(256, 8) void mm1_count_kernel(
        const float* __restrict__ x, const float* __restrict__ W1,
        float* __restrict__ T1, int n, int mb,
        const int* __restrict__ ei, int E,
        int* __restrict__ cnt_src, int* __restrict__ cnt_dst,
        int* __restrict__ tmp_slot) {
    int g = (int)blockIdx.x;
    bool is_mm = (g < 3 * mb) && (g % 3 == 0);
    if (!is_mm) {
        int ci = (g < 3 * mb) ? (g - (g + 2) / 3) : (g - mb);
        int e = ci * 256 + threadIdx.x;
        if (e < E) {
            int s = ei[e];
            int d = ei[E + e];
            atomicAdd(&cnt_src[s], 1);
            tmp_slot[e] = atomicAdd(&cnt_dst[d], 1);
        }
        return;
    }
    int bm = g / 3;
    __shared__ float Xl[32][128];
    int t = threadIdx.x;
    int row0 = bm * 32;
    for (int i = t; i < 32 * 32; i += 256) {
        int r = i >> 5, k4 = i & 31;
        int gr = row0 + r;
        float4 xv = make_float4(0.f, 0.f, 0.f, 0.f);
        if (gr < n) xv = reinterpret_cast<const float4*>(x)[(size_t)gr * 32 + k4];
        reinterpret_cast<float4*>(&Xl[r][0])[k4] = xv;
    }
    __syncthreads();
    int wv = t >> 6, lane = t & 63;
    int c0 = lane, c1 = lane + 64;
    float acc0[8], acc1[8];
    #pragma unroll
    for (int r = 0; r < 8; ++r) { acc0[r] = 0.f; acc1[r] = 0.f; }
    int rbase = wv * 8;
    const float* Wp0 = W1 + c0;
    const float* Wp1 = W1 + c1;
    for (int k = 0; k < 128; k += 4) {
        float w00 = Wp0[(k + 0) * 128], w10 = Wp1[(k + 0) * 128];
        float w01 = Wp0[(k + 1) * 128], w11 = Wp1[(k + 1) * 128];
        float w02 = Wp0[(k + 2) * 128], w12 = Wp1[(k + 2) * 128];
        float w03 = Wp0[(k + 3) * 128], w13 = Wp1[(k + 3) * 128];
        #pragma unroll
        for (int r = 0; r < 8; ++r) {
            float4 xv = *reinterpret_cast<const float4*>(&Xl[rbase + r][k]);
            acc0[r] = fmaf(xv.x, w00, acc0[r]);
            acc1[r] = fmaf(xv.x, w10, acc1[r]);
            acc0[r] = fmaf(xv.y, w01, acc0[r]);
            acc1[r] = fmaf(xv.y, w11, acc1[r]);
            acc0[r] = fmaf(xv.z, w02, acc0[r]);
            acc1[r] = fmaf(xv.z, w12, acc1[r]);
            acc0[r] = fmaf(xv.w, w03, acc0[r]);
            acc1[r] = fmaf(xv.w, w13, acc1[r]);
        }
    }
    #pragma unroll
    for (int r = 0; r < 8; ++r) {
        int gr = row0 + rbase + r;
        if (gr < n) {
            T1[(size_t)gr * 128 + c0] = acc0[r];
            T1[(size_t)gr * 128 + c1] = acc1[r];
        }
    }
}

__global__ __launch_bounds__(256) void scan_blocksum(const int* __restrict__ deg_in, int n,
                                                     int* __restrict__ partials) {
    __shared__ int red[256];
    int t = threadIdx.x;
    int base = blockIdx.x * SCAN_CHUNK;
    int s = 0;
    for (int i = t; i < SCAN_CHUNK; i += 256) {
        int idx = base + i;
        if (idx < n) s += deg_in[idx];
    }
    red[t] = s;
    __syncthreads();
    for (int off = 128; off > 0; off >>= 1) {
        if (t < off) red[t] += red[t + off];
        __syncthreads();
    }
    if (t == 0) partials[blockIdx.x] = red[0];
}

__global__ __launch_bounds__(256) void scan_partials(int* __restrict__ partials, int nparts,
                                                     int* __restrict__ row_ptr, int n) {
    __shared__ int s[256];
    int t = threadIdx.x;
    s[t] = (t < nparts) ? partials[t] : 0;
    __syncthreads();
    for (int off = 1; off < 256; off <<= 1) {
        int v = (t >= off) ? s[t - off] : 0;
        __syncthreads();
        s[t] += v;
        __syncthreads();
    }
    int incl = s[t];
    int excl = incl - ((t < nparts) ? partials[t] : 0);
    if (t < nparts) partials[t] = excl;
    if (t == 255) row_ptr[n] = incl;
}

// Per-chunk exclusive scan -> row_ptr, fused norm compute.
__global__ __launch_bounds__(256) void scan_emit(const int* __restrict__ deg_in,
                                                 const int* __restrict__ deg_out,
                                                 const int* __restrict__ partials, int n,
                                                 int* __restrict__ row_ptr,
                                                 float* __restrict__ norm_src,
                                                 float* __restrict__ norm_dst) {
    __shared__ int tsum[256];
    int t = threadIdx.x;
    int base = blockIdx.x * SCAN_CHUNK + t * 16;
    int local[16];
    int s = 0;
    #pragma unroll
    for (int i = 0; i < 16; ++i) {
        int idx = base + i;
        int v = (idx < n) ? deg_in[idx] : 0;
        local[i] = v;
        s += v;
    }
    tsum[t] = s;
    __syncthreads();
    for (int off = 1; off < 256; off <<= 1) {
        int v = (t >= off) ? tsum[t - off] : 0;
        __syncthreads();
        tsum[t] += v;
        __syncthreads();
    }
    int run = partials[blockIdx.x] + (t ? tsum[t - 1] : 0);
    #pragma unroll
    for (int i = 0; i < 16; ++i) {
        int idx = base + i;
        if (idx < n) {
            row_ptr[idx] = run;
            run += local[i];
            int di = local[i] > 0 ? local[i] : 1;
            int dq = deg_out[idx] > 0 ? deg_out[idx] : 1;
            norm_dst[idx] = rsqrtf((float)di);
            norm_src[idx] = rsqrtf((float)dq);
        }
    }
}

// Heterogeneous: blocks [0,eb) scatter CSR cols (atomic-free); blocks
// [eb,eb+cb) convert T1 to pre-scaled bf16 table xb = bf16(ns*T1).
__global__ __launch_bounds__(256) void scatter_convert_kernel(const int* __restrict__ ei, int E,
        const int* __restrict__ row_ptr, const int* __restrict__ tmp_slot,
        int* __restrict__ col, int eb,
        const float* __restrict__ T1, const float* __restrict__ ns,
        ushort* __restrict__ xb, int n) {
    if ((int)blockIdx.x < eb) {
        int e = blockIdx.x * 256 + threadIdx.x;
        if (e < E) {
            int s = ei[e];
            int d = ei[E + e];
            col[row_ptr[d] + tmp_slot[e]] = s;
        }
    } else {
        int i = ((int)blockIdx.x - eb) * 256 + threadIdx.x;
        if (i < n * 32) {
            int row = i >> 5;
            float s = ns[row];
            float4 v = reinterpret_cast<const float4*>(T1)[i];
            ushort4 o;
            o.x = f2bf(v.x * s); o.y = f2bf(v.y * s);
            o.z = f2bf(v.z * s); o.w = f2bf(v.w * s);
            reinterpret_cast<ushort4*>(xb)[i] = o;
        }
    }
}

// One wave per node: out[v][:] = sum_{u->v} xb[u][:] (bf16 rows, fp32 accum).
// 4 edges per iteration: 16 lanes x 8 dims each (16B loads); quarter-wave combine at end.
__global__ __launch_bounds__(256) void agg128_kernel(const ushort* __restrict__ xb,
        const int* __restrict__ row_ptr, const int* __restrict__ col,
        float* __restrict__ out, int n) {
    int wid  = (blockIdx.x * blockDim.x + threadIdx.x) >> 6;
    int lane = threadIdx.x & 63;
    if (wid >= n) return;
    int start = row_ptr[wid], end = row_ptr[wid + 1];
    int quarter = lane >> 4, l4 = lane & 15;
    float acc[8];
    #pragma unroll
    for (int i = 0; i < 8; ++i) acc[i] = 0.f;
    for (int b = start; b < end; b += 64) {
        int m = end - b; if (m > 64) m = 64;
        int u = 0;
        if (lane < m) u = col[b + lane];
        for (int j = 0; j < m; j += 4) {
            int jj = j + quarter;
            int uu = __shfl(u, jj);
            if (jj < m) {
                const uint4 v = *reinterpret_cast<const uint4*>(xb + (size_t)uu * 128 + 8 * l4);
                float f0, f1;
                unpack2(v.x, f0, f1); acc[0] += f0; acc[1] += f1;
                unpack2(v.y, f0, f1); acc[2] += f0; acc[3] += f1;
                unpack2(v.z, f0, f1); acc[4] += f0; acc[5] += f1;
                unpack2(v.w, f0, f1); acc[6] += f0; acc[7] += f1;
            }
        }
    }
    #pragma unroll
    for (int i = 0; i < 8; ++i) {
        acc[i] += __shfl_xor(acc[i], 16);
        acc[i] += __shfl_xor(acc[i], 32);
    }
    if (lane < 16) {
        float* op = out + (size_t)wid * 128 + 8 * lane;
        *reinterpret_cast<float4*>(op)     = make_float4(acc[0], acc[1], acc[2], acc[3]);
        *reinterpret_cast<float4*>(op + 4) = make_float4(acc[4], acc[5], acc[6], acc[7]);
    }
}

// Layer 2: X' = relu(nd*agg1 + b1) applied at LDS-load; acc = X'@W2;
// epilogue writes xb2 = bf16(ns*acc). 32-row tiles; W2 streamed from L2.
__global__ __launch_bounds__(256, 4) void mm128_l2_kernel(const float* __restrict__ agg,
        const float* __restrict__ W2, const float* __restrict__ b1,
        const float* __restrict__ norm_dst, const float* __restrict__ norm_src,
        ushort* __restrict__ out, int n) {
    __shared__ float Xl[32][128];
    int t = threadIdx.x;
    int row0 = blockIdx.x * 32;
    for (int i = t; i < 32 * 32; i += 256) {
        int r = i >> 5, k4 = i & 31;
        int gr = row0 + r;
        float4 xv = make_float4(0.f, 0.f, 0.f, 0.f);
        if (gr < n) {
            xv = reinterpret_cast<const float4*>(agg)[(size_t)gr * 32 + k4];
            float4 bb = reinterpret_cast<const float4*>(b1)[k4];
            float nd = norm_dst[gr];
            xv.x = fmaxf(fmaf(nd, xv.x, bb.x), 0.f);
            xv.y = fmaxf(fmaf(nd, xv.y, bb.y), 0.f);
            xv.z = fmaxf(fmaf(nd, xv.z, bb.z), 0.f);
            xv.w = fmaxf(fmaf(nd, xv.w, bb.w), 0.f);
        }
        reinterpret_cast<float4*>(&Xl[r][0])[k4] = xv;
    }
    __syncthreads();
    int wv = t >> 6, lane = t & 63;
    int c0 = lane, c1 = lane + 64;
    float acc0[8], acc1[8];
    #pragma unroll
    for (int r = 0; r < 8; ++r) { acc0[r] = 0.f; acc1[r] = 0.f; }
    int rbase = wv * 8;
    const float* Wp0 = W2 + c0;
    const float* Wp1 = W2 + c1;
    for (int k = 0; k < 128; k += 4) {
        float w00 = Wp0[(k + 0) * 128], w10 = Wp1[(k + 0) * 128];
        float w01 = Wp0[(k + 1) * 128], w11 = Wp1[(k + 1) * 128];
        float w02 = Wp0[(k + 2) * 128], w12 = Wp1[(k + 2) * 128];
        float w03 = Wp0[(k + 3) * 128], w13 = Wp1[(k + 3) * 128];
        #pragma unroll
        for (int r = 0; r < 8; ++r) {
            float4 xv = *reinterpret_cast<const float4*>(&Xl[rbase + r][k]);
            acc0[r] = fmaf(xv.x, w00, acc0[r]);
            acc1[r] = fmaf(xv.x, w10, acc1[r]);
            acc0[r] = fmaf(xv.y, w01, acc0[r]);
            acc1[r] = fmaf(xv.y, w11, acc1[r]);
            acc0[r] = fmaf(xv.z, w02, acc0[r]);
            acc1[r] = fmaf(xv.z, w12, acc1[r]);
            acc0[r] = fmaf(xv.w, w03, acc0[r]);
            acc1[r] = fmaf(xv.w, w13, acc1[r]);
        }
    }
    #pragma unroll
    for (int r = 0; r < 8; ++r) {
        int gr = row0 + rbase + r;
        if (gr < n) {
            float ns = norm_src[gr];
            out[(size_t)gr * 128 + c0] = f2bf(ns * acc0[r]);
            out[(size_t)gr * 128 + c1] = f2bf(ns * acc1[r]);
        }
    }
}

// Layer 3 mm: X'' = ns*relu(nd*agg2 + b2) at load; y = X''@W3 (fp32, 40 cols).
__global__ __launch_bounds__(256, 4) void mm40_l3_kernel(const float* __restrict__ agg,
        const float* __restrict__ W3, const float* __restrict__ b2,
        const float* __restrict__ norm_dst, const float* __restrict__ norm_src,
        float* __restrict__ y, int n) {
    __shared__ float Xl[32][128];
    int t = threadIdx.x;
    int row0 = blockIdx.x * 32;
    for (int i = t; i < 32 * 32; i += 256) {
        int r = i >> 5, k4 = i & 31;
        int gr = row0 + r;
        float4 xv = make_float4(0.f, 0.f, 0.f, 0.f);
        if (gr < n) {
            xv = reinterpret_cast<const float4*>(agg)[(size_t)gr * 32 + k4];
            float4 bb = reinterpret_cast<const float4*>(b2)[k4];
            float nd = norm_dst[gr], ns = norm_src[gr];
            xv.x = ns * fmaxf(fmaf(nd, xv.x, bb.x), 0.f);
            xv.y = ns * fmaxf(fmaf(nd, xv.y, bb.y), 0.f);
            xv.z = ns * fmaxf(fmaf(nd, xv.z, bb.z), 0.f);
            xv.w = ns * fmaxf(fmaf(nd, xv.w, bb.w), 0.f);
        }
        reinterpret_cast<float4*>(&Xl[r][0])[k4] = xv;
    }
    __syncthreads();
    int wv = t >> 6, lane = t & 63;
    int c = (lane < 40) ? lane : 0;
    float acc[8];
    #pragma unroll
    for (int r = 0; r < 8; ++r) acc[r] = 0.f;
    int rbase = wv * 8;
    const float* Wp = W3 + c;
    for (int k = 0; k < 128; k += 2) {
        float w0 = Wp[(k + 0) * 40];
        float w1 = Wp[(k + 1) * 40];
        #pragma unroll
        for (int r = 0; r < 8; ++r) {
            float2 xv = *reinterpret_cast<const float2*>(&Xl[rbase + r][k]);
            acc[r] = fmaf(xv.x, w0, acc[r]);
            acc[r] = fmaf(xv.y, w1, acc[r]);
        }
    }
    if (lane < 40) {
        #pragma unroll
        for (int r = 0; r < 8; ++r) {
            int gr = row0 + rbase + r;
            if (gr < n) y[(size_t)gr * 40 + lane] = acc[r];
        }
    }
}

// out[v][c] = norm_dst[v] * sum_{u->v} y[u][c] + b3[c], c < 40. One wave/node.
__global__ __launch_bounds__(256) void agg40_kernel(const float* __restrict__ y,
        const int* __restrict__ row_ptr, const int* __restrict__ col,
        const float* __restrict__ norm_dst, const float* __restrict__ b3,
        float* __restrict__ out, int n) {
    int wid  = (blockIdx.x * blockDim.x + threadIdx.x) >> 6;
    int lane = threadIdx.x & 63;
    if (wid >= n) return;
    int start = row_ptr[wid], end = row_ptr[wid + 1];
    float acc = 0.f;
    for (int b = start; b < end; b += 64) {
        int m = end - b; if (m > 64) m = 64;
        int u = 0;
        if (lane < m) u = col[b + lane];
        for (int j = 0; j < m; ++j) {
            int uu = __shfl(u, j);
            if (lane < 40) acc += y[(size_t)uu * 40 + lane];
        }
    }
    if (lane < 40) out[(size_t)wid * 40 + lane] = norm_dst[wid] * acc + b3[lane];
}

extern "C" void kernel_launch(void* const* d_in, const int* in_sizes, int n_in,
                              void* d_out, int out_size, void* d_ws, size_t ws_size,
                              hipStream_t stream) {
    const float* features = (const float*)d_in[0];
    const int*   ei       = (const int*)d_in[1];
    const float* W1 = (const float*)d_in[2];
    const float* b1 = (const float*)d_in[3];
    const float* W2 = (const float*)d_in[4];
    const float* b2 = (const float*)d_in[5];
    const float* W3 = (const float*)d_in[6];
    const float* b3 = (const float*)d_in[7];

    const int n = in_sizes[0] / 128;
    const int E = in_sizes[1] / 2;

    char* w = (char*)d_ws;
    auto alloc = [&](size_t bytes) {
        char* p = w;
        w += (bytes + 255) & ~(size_t)255;
        return p;
    };
    int*    deg      = (int*)   alloc((size_t)2 * n * 4);  // cnt_src | cnt_dst
    float*  norm_src = (float*) alloc((size_t)n * 4);
    float*  norm_dst = (float*) alloc((size_t)n * 4);
    int*    row_ptr  = (int*)   alloc((size_t)(n + 1) * 4);
    int*    partials = (int*)   alloc((size_t)256 * 4);
    int*    tmp_slot = (int*)   alloc((size_t)E * 4);
    int*    col      = (int*)   alloc((size_t)E * 4);
    ushort* xb       = (ushort*)alloc((size_t)n * 128 * 2);  // bf16 table; y aliases this
    float*  bufA     = (float*) alloc((size_t)n * 128 * 4);  // T1 / agg buffer (aliased safely)

    int* deg_out = deg;      // cnt_src
    int* deg_in  = deg + n;  // cnt_dst
    float* T1 = bufA;        // T1 consumed by convert before agg1 overwrites bufA
    float* y  = (float*)xb;  // y (n*40 fp32) aliases xb; xb2 fully consumed
                             // by agg2 before mm40 writes y

    hipMemsetAsync(deg, 0, (size_t)2 * n * 4, stream);

    int eb = (E + 255) / 256;
    int mb = (n + 31) / 32;
    int sb = (n + SCAN_CHUNK - 1) / SCAN_CHUNK;
    int cb = (n * 32 + 255) / 256;
    int ab = (n + 3) / 4;

    mm1_count_kernel<<<mb + eb, 256, 0, stream>>>(features, W1, T1, n, mb,
                                                  ei, E, deg_out, deg_in, tmp_slot);
    scan_blocksum<<<sb, 256, 0, stream>>>(deg_in, n, partials);
    scan_partials<<<1, 256, 0, stream>>>(partials, sb, row_ptr, n);
    scan_emit<<<sb, 256, 0, stream>>>(deg_in, deg_out, partials, n,
                                      row_ptr, norm_src, norm_dst);
    scatter_convert_kernel<<<eb + cb, 256, 0, stream>>>(ei, E, row_ptr, tmp_slot, col, eb,
                                                        T1, norm_src, xb, n);
    agg128_kernel<<<ab, 256, 0, stream>>>(xb, row_ptr, col, bufA, n);
    mm128_l2_kernel<<<mb, 256, 0, stream>>>(bufA, W2, b1, norm_dst, norm_src, xb, n);
    agg128_kernel<<<ab, 256, 0, stream>>>(xb, row_ptr, col, bufA, n);
    mm40_l3_kernel<<<mb, 256, 0, stream>>>(bufA, W3, b2, norm_dst, norm_src, y, n);
    agg40_kernel<<<ab, 256, 0, stream>>>(y, row_ptr, col, norm_dst, b3, (float*)d_out, n);
}

// Round 10
// 279.899 us; speedup vs baseline: 1.1487x; 1.1487x over previous
//
#include <hip/hip_runtime.h>

// GCN 3-layer forward on MI355X.
// CSR build WITHOUT global atomics (memory-side RMW ceiling ~22G/s measured):
//   hist_rank:  per-block LDS histograms over dst>>8 / src>>8 + in-block ranks
//   scan:       hierarchical exclusive scan of bucket-major histograms (both)
//   scatter:    slot = scanned base + rank; packD=(dlow<<24|src) to dst-buckets,
//               src low byte to src-buckets
//   bucket:     per dst-bucket LDS count+scan -> row_ptr/norm_dst + ranked col;
//               per src-bucket LDS count -> norm_src
// Then (segment_sum(M)@W == segment_sum(M@W), matmul before aggregation):
//   mm1: T1 = x@W1; convert: xb = bf16(ns*T1)
//   agg128 -> mm128_l2 (relu/norm fused, bf16 out) -> agg128 -> mm40_l3 -> agg40

#define EPB 4096          // edges per partition block (256 threads x 16)
#define SCAN_CHUNK 4096

__device__ __forceinline__ ushort f2bf(float f) {
    unsigned u = __float_as_uint(f);
    unsigned r = (u + 0x7fffu + ((u >> 16) & 1u)) >> 16;  // RN-even
    return (ushort)r;
}
__device__ __forceinline__ void unpack2(unsigned w, float& lo, float& hi) {
    lo = __uint_as_float(w << 16);
    hi = __uint_as_float(w & 0xffff0000u);
}

// Pass 1: per-block LDS histograms (dst>>8, src>>8) + in-block ranks.
__global__ __launch_bounds__(256) void hist_rank_kernel(const int* __restrict__ ei, int E,
        int nblk1, int NB, int* __restrict__ hist_all,
        ushort* __restrict__ rankD, ushort* __restrict__ rankS) {
    __shared__ int hd[512];
    __shared__ int hs[512];
    int t = threadIdx.x, blk = blockIdx.x;
    for (int i = t; i < 512; i += 256) { hd[i] = 0; hs[i] = 0; }
    __syncthreads();
    int base = blk * EPB;
    #pragma unroll
    for (int j = 0; j < 16; ++j) {
        int e = base + j * 256 + t;
        if (e < E) {
            int s = ei[e], d = ei[E + e];
            rankS[e] = (ushort)atomicAdd(&hs[s >> 8], 1);
            rankD[e] = (ushort)atomicAdd(&hd[d >> 8], 1);
        }
    }
    __syncthreads();
    int L = NB * nblk1;
    for (int b = t; b < NB; b += 256) {
        hist_all[b * nblk1 + blk]     = hd[b];
        hist_all[L + b * nblk1 + blk] = hs[b];
    }
}

// Generic hierarchical exclusive scan over data[0..L2)
__global__ __launch_bounds__(256) void scanA_kernel(const int* __restrict__ data, int L2,
                                                    int* __restrict__ partials) {
    __shared__ int red[256];
    int t = threadIdx.x;
    int base = blockIdx.x * SCAN_CHUNK;
    int s = 0;
    for (int i = t; i < SCAN_CHUNK; i += 256) {
        int idx = base + i;
        if (idx < L2) s += data[idx];
    }
    red[t] = s;
    __syncthreads();
    for (int off = 128; off > 0; off >>= 1) {
        if (t < off) red[t] += red[t + off];
        __syncthreads();
    }
    if (t == 0) partials[blockIdx.x] = red[0];
}

__global__ __launch_bounds__(256) void scanB_kernel(int* __restrict__ partials, int nparts) {
    __shared__ int s[256];
    int t = threadIdx.x;
    s[t] = (t < nparts) ? partials[t] : 0;
    __syncthreads();
    for (int off = 1; off < 256; off <<= 1) {
        int v = (t >= off) ? s[t - off] : 0;
        __syncthreads();
        s[t] += v;
        __syncthreads();
    }
    if (t < nparts) partials[t] = s[t] - partials[t];
}

__global__ __launch_bounds__(256) void scanC_kernel(int* __restrict__ data, int L2,
                                                    const int* __restrict__ partials) {
    __shared__ int tsum[256];
    int t = threadIdx.x;
    int base = blockIdx.x * SCAN_CHUNK + t * 16;
    int local[16];
    int s = 0;
    #pragma unroll
    for (int i = 0; i < 16; ++i) {
        int idx = base + i;
        int v = (idx < L2) ? data[idx] : 0;
        local[i] = v;
        s += v;
    }
    tsum[t] = s;
    __syncthreads();
    for (int off = 1; off < 256; off <<= 1) {
        int v = (t >= off) ? tsum[t - off] : 0;
        __syncthreads();
        tsum[t] += v;
        __syncthreads();
    }
    int run = partials[blockIdx.x] + (t ? tsum[t - 1] : 0);
    #pragma unroll
    for (int i = 0; i < 16; ++i) {
        int idx = base + i;
        if (idx < L2) {
            data[idx] = run;
            run += local[i];
        }
    }
}

// Pass 1c: scatter into bucket partitions using scanned bases + stored ranks.
__global__ __launch_bounds__(256) void scatter_part_kernel(const int* __restrict__ ei, int E,
        int nblk1, int NB, const int* __restrict__ hist_all,
        const ushort* __restrict__ rankD, const ushort* __restrict__ rankS,
        unsigned* __restrict__ packD, unsigned char* __restrict__ srcb) {
    int t = threadIdx.x, blk = blockIdx.x;
    int base = blk * EPB;
    int L = NB * nblk1;
    #pragma unroll
    for (int j = 0; j < 16; ++j) {
        int e = base + j * 256 + t;
        if (e < E) {
            int s = ei[e], d = ei[E + e];
            int posD = hist_all[(d >> 8) * nblk1 + blk] + (int)rankD[e];
            packD[posD] = ((unsigned)(d & 255) << 24) | (unsigned)s;
            int posS = hist_all[L + (s >> 8) * nblk1 + blk] - E + (int)rankS[e];
            srcb[posS] = (unsigned char)(s & 255);
        }
    }
}

// Pass 2: blocks [0,NB): dst-bucket -> row_ptr, norm_dst, ranked col placement.
//         blocks [NB,2NB): src-bucket -> norm_src. LDS atomics only.
__global__ __launch_bounds__(256) void bucket_kernel(const unsigned* __restrict__ packD,
        const unsigned char* __restrict__ srcb, const int* __restrict__ hist_all,
        int nblk1, int NB, int n, int E,
        int* __restrict__ row_ptr, int* __restrict__ col,
        float* __restrict__ norm_src, float* __restrict__ norm_dst) {
    int t = threadIdx.x;
    __shared__ int cnt[256];
    __shared__ int incl[256];
    __shared__ int cur[256];
    if ((int)blockIdx.x < NB) {
        int B = blockIdx.x;
        int s0 = hist_all[B * nblk1];
        int s1 = (B + 1 < NB) ? hist_all[(B + 1) * nblk1] : E;
        cnt[t] = 0;
        __syncthreads();
        for (int i = s0 + t; i < s1; i += 256)
            atomicAdd(&cnt[packD[i] >> 24], 1);
        __syncthreads();
        int v = cnt[t];
        incl[t] = v;
        __syncthreads();
        for (int off = 1; off < 256; off <<= 1) {
            int w = (t >= off) ? incl[t - off] : 0;
            __syncthreads();
            incl[t] += w;
            __syncthreads();
        }
        int excl = incl[t] - v;
        cur[t] = excl;
        int node = B * 256 + t;
        if (node < n) {
            row_ptr[node] = s0 + excl;
            norm_dst[node] = rsqrtf((float)(v > 0 ? v : 1));
        }
        if (B == NB - 1 && t == 0) row_ptr[n] = E;
        __syncthreads();
        for (int i = s0 + t; i < s1; i += 256) {
            unsigned p = packD[i];
            int r = atomicAdd(&cur[p >> 24], 1);
            col[s0 + r] = (int)(p & 0xFFFFFFu);
        }
    } else {
        int B = (int)blockIdx.x - NB;
        int L = NB * nblk1;
        int s0 = hist_all[L + B * nblk1] - E;
        int s1 = (B + 1 < NB) ? (hist_all[L + (B + 1) * nblk1] - E) : E;
        cnt[t] = 0;
        __syncthreads();
        for (int i = s0 + t; i < s1; i += 256)
            atomicAdd(&cnt[srcb[i]], 1);
        __syncthreads();
        int node = B * 256 + t;
        if (node < n) {
            int v = cnt[t];
            norm_src[node] = rsqrtf((float)(v > 0 ? v : 1));
        }
    }
}

// T1 = x @ W1 (raw fp32). 32-row tiles; W1 streamed from L2.
__global__ __launch_bounds__(256, 4) void mm1_kernel(const float* __restrict__ x,
        const float* __restrict__ W1, float* __restrict__ T1, int n) {
    __shared__ float Xl[32][128];
    int t = threadIdx.x;
    int row0 = blockIdx.x * 32;
    for (int i = t; i < 32 * 32; i += 256) {
        int r = i >> 5, k4 = i & 31;
        int gr = row0 + r;
        float4 xv = make_float4(0.f, 0.f, 0.f, 0.f);
        if (gr < n) xv = reinterpret_cast<const float4*>(x)[(size_t)gr * 32 + k4];
        reinterpret_cast<float4*>(&Xl[r][0])[k4] = xv;
    }
    __syncthreads();
    int wv = t >> 6, lane = t & 63;
    int c0 = lane, c1 = lane + 64;
    float acc0[8], acc1[8];
    #pragma unroll
    for (int r = 0; r < 8; ++r) { acc0[r] = 0.f; acc1[r] = 0.f; }
    int rbase = wv * 8;
    const float* Wp0 = W1 + c0;
    const float* Wp1 = W1 + c1;
    for (int k = 0; k < 128; k += 4) {
        float w00 = Wp0[(k + 0) * 128], w10 = Wp1[(k + 0) * 128];
        float w01 = Wp0[(k + 1) * 128], w11 = Wp1[(k + 1) * 128];
        float w02 = Wp0[(k + 2) * 128], w12 = Wp1[(k + 2) * 128];
        float w03 = Wp0[(k + 3) * 128], w13 = Wp1[(k + 3) * 128];
        #pragma unroll
        for (int r = 0; r < 8; ++r) {
            float4 xv = *reinterpret_cast<const float4*>(&Xl[rbase + r][k]);
            acc0[r] = fmaf(xv.x, w00, acc0[r]);
            acc1[r] = fmaf(xv.x, w10, acc1[r]);
            acc0[r] = fmaf(xv.y, w01, acc0[r]);
            acc1[r] = fmaf(xv.y, w11, acc1[r]);
            acc0[r] = fmaf(xv.z, w02, acc0[r]);
            acc1[r] = fmaf(xv.z, w12, acc1[r]);
            acc0[r] = fmaf(xv.w, w03, acc0[r]);
            acc1[r] = fmaf(xv.w, w13, acc1[r]);
        }
    }
    #pragma unroll
    for (int r = 0; r < 8; ++r) {
        int gr = row0 + rbase + r;
        if (gr < n) {
            T1[(size_t)gr * 128 + c0] = acc0[r];
            T1[(size_t)gr * 128 + c1] = acc1[r];
        }
    }
}

// xb = bf16(ns * T1)
__global__ __launch_bounds__(256) void convert_kernel(const float* __restrict__ T1,
        const float* __restrict__ ns, ushort* __restrict__ xb, int n) {
    int i = blockIdx.x * blockDim.x + threadIdx.x;
    if (i >= n * 32) return;
    int row = i >> 5;
    float s = ns[row];
    float4 v = reinterpret_cast<const float4*>(T1)[i];
    ushort4 o;
    o.x = f2bf(v.x * s); o.y = f2bf(v.y * s);
    o.z = f2bf(v.z * s); o.w = f2bf(v.w * s);
    reinterpret_cast<ushort4*>(xb)[i] = o;
}

// One wave per node: out[v][:] = sum_{u->v} xb[u][:] (bf16 rows, fp32 accum).
__global__ __launch_bounds__(256) void agg128_kernel(const ushort* __restrict__ xb,
        const int* __restrict__ row_ptr, const int* __restrict__ col,
        float* __restrict__ out, int n) {
    int wid  = (blockIdx.x * blockDim.x + threadIdx.x) >> 6;
    int lane = threadIdx.x & 63;
    if (wid >= n) return;
    int start = row_ptr[wid], end = row_ptr[wid + 1];
    int quarter = lane >> 4, l4 = lane & 15;
    float acc[8];
    #pragma unroll
    for (int i = 0; i < 8; ++i) acc[i] = 0.f;
    for (int b = start; b < end; b += 64) {
        int m = end - b; if (m > 64) m = 64;
        int u = 0;
        if (lane < m) u = col[b + lane];
        for (int j = 0; j < m; j += 4) {
            int jj = j + quarter;
            int uu = __shfl(u, jj);
            if (jj < m) {
                const uint4 v = *reinterpret_cast<const uint4*>(xb + (size_t)uu * 128 + 8 * l4);
                float f0, f1;
                unpack2(v.x, f0, f1); acc[0] += f0; acc[1] += f1;
                unpack2(v.y, f0, f1); acc[2] += f0; acc[3] += f1;
                unpack2(v.z, f0, f1); acc[4] += f0; acc[5] += f1;
                unpack2(v.w, f0, f1); acc[6] += f0; acc[7] += f1;
            }
        }
    }
    #pragma unroll
    for (int i = 0; i < 8; ++i) {
        acc[i] += __shfl_xor(acc[i], 16);
        acc[i] += __shfl_xor(acc[i], 32);
    }
    if (lane < 16) {
        float* op = out + (size_t)wid * 128 + 8 * lane;
        *reinterpret_cast<float4*>(op)     = make_float4(acc[0], acc[1], acc[2], acc[3]);
        *reinterpret_cast<float4*>(op + 4) = make_float4(acc[4], acc[5], acc[6], acc[7]);
    }
}

// Layer 2: X' = relu(nd*agg1 + b1) at LDS-load; out = bf16(ns * (X'@W2)).
__global__ __launch_bounds__(256, 4) void mm128_l2_kernel(const float* __restrict__ agg,
        const float* __restrict__ W2, const float* __restrict__ b1,
        const float* __restrict__ norm_dst, const float* __restrict__ norm_src,
        ushort* __restrict__ out, int n) {
    __shared__ float Xl[32][128];
    int t = threadIdx.x;
    int row0 = blockIdx.x * 32;
    for (int i = t; i < 32 * 32; i += 256) {
        int r = i >> 5, k4 = i & 31;
        int gr = row0 + r;
        float4 xv = make_float4(0.f, 0.f, 0.f, 0.f);
        if (gr < n) {
            xv = reinterpret_cast<const float4*>(agg)[(size_t)gr * 32 + k4];
            float4 bb = reinterpret_cast<const float4*>(b1)[k4];
            float nd = norm_dst[gr];
            xv.x = fmaxf(fmaf(nd, xv.x, bb.x), 0.f);
            xv.y = fmaxf(fmaf(nd, xv.y, bb.y), 0.f);
            xv.z = fmaxf(fmaf(nd, xv.z, bb.z), 0.f);
            xv.w = fmaxf(fmaf(nd, xv.w, bb.w), 0.f);
        }
        reinterpret_cast<float4*>(&Xl[r][0])[k4] = xv;
    }
    __syncthreads();
    int wv = t >> 6, lane = t & 63;
    int c0 = lane, c1 = lane + 64;
    float acc0[8], acc1[8];
    #pragma unroll
    for (int r = 0; r < 8; ++r) { acc0[r] = 0.f; acc1[r] = 0.f; }
    int rbase = wv * 8;
    const float* Wp0 = W2 + c0;
    const float* Wp1 = W2 + c1;
    for (int k = 0; k < 128; k += 4) {
        float w00 = Wp0[(k + 0) * 128], w10 = Wp1[(k + 0) * 128];
        float w01 = Wp0[(k + 1) * 128], w11 = Wp1[(k + 1) * 128];
        float w02 = Wp0[(k + 2) * 128], w12 = Wp1[(k + 2) * 128];
        float w03 = Wp0[(k + 3) * 128], w13 = Wp1[(k + 3) * 128];
        #pragma unroll
        for (int r = 0; r < 8; ++r) {
            float4 xv = *reinterpret_cast<const float4*>(&Xl[rbase + r][k]);
            acc0[r] = fmaf(xv.x, w00, acc0[r]);
            acc1[r] = fmaf(xv.x, w10, acc1[r]);
            acc0[r] = fmaf(xv.y, w01, acc0[r]);
            acc1[r] = fmaf(xv.y, w11, acc1[r]);
            acc0[r] = fmaf(xv.z, w02, acc0[r]);
            acc1[r] = fmaf(xv.z, w12, acc1[r]);
            acc0[r] = fmaf(xv.w, w03, acc0[r]);
            acc1[r] = fmaf(xv.w, w13, acc1[r]);
        }
    }
    #pragma unroll
    for (int r = 0; r < 8; ++r) {
        int gr = row0 + rbase + r;
        if (gr < n) {
            float ns = norm_src[gr];
            out[(size_t)gr * 128 + c0] = f2bf(ns * acc0[r]);
            out[(size_t)gr * 128 + c1] = f2bf(ns * acc1[r]);
        }
    }
}

// Layer 3 mm: X'' = ns*relu(nd*agg2 + b2) at load; y = X''@W3 (fp32, 40 cols).
__global__ __launch_bounds__(256, 4) void mm40_l3_kernel(const float* __restrict__ agg,
        const float* __restrict__ W3, const float* __restrict__ b2,
        const float* __restrict__ norm_dst, const float* __restrict__ norm_src,
        float* __restrict__ y, int n) {
    __shared__ float Xl[32][128];
    int t = threadIdx.x;
    int row0 = blockIdx.x * 32;
    for (int i = t; i < 32 * 32; i += 256) {
        int r = i >> 5, k4 = i & 31;
        int gr = row0 + r;
        float4 xv = make_float4(0.f, 0.f, 0.f, 0.f);
        if (gr < n) {
            xv = reinterpret_cast<const float4*>(agg)[(size_t)gr * 32 + k4];
            float4 bb = reinterpret_cast<const float4*>(b2)[k4];
            float nd = norm_dst[gr], ns = norm_src[gr];
            xv.x = ns * fmaxf(fmaf(nd, xv.x, bb.x), 0.f);
            xv.y = ns * fmaxf(fmaf(nd, xv.y, bb.y), 0.f);
            xv.z = ns * fmaxf(fmaf(nd, xv.z, bb.z), 0.f);
            xv.w = ns * fmaxf(fmaf(nd, xv.w, bb.w), 0.f);
        }
        reinterpret_cast<float4*>(&Xl[r][0])[k4] = xv;
    }
    __syncthreads();
    int wv = t >> 6, lane = t & 63;
    int c = (lane < 40) ? lane : 0;
    float acc[8];
    #pragma unroll
    for (int r = 0; r < 8; ++r) acc[r] = 0.f;
    int rbase = wv * 8;
    const float* Wp = W3 + c;
    for (int k = 0; k < 128; k += 2) {
        float w0 = Wp[(k + 0) * 40];
        float w1 = Wp[(k + 1) * 40];
        #pragma unroll
        for (int r = 0; r < 8; ++r) {
            float2 xv = *reinterpret_cast<const float2*>(&Xl[rbase + r][k]);
            acc[r] = fmaf(xv.x, w0, acc[r]);
            acc[r] = fmaf(xv.y, w1, acc[r]);
        }
    }
    if (lane < 40) {
        #pragma unroll
        for (int r = 0; r < 8; ++r) {
            int gr = row0 + rbase + r;
            if (gr < n) y[(size_t)gr * 40 + lane] = acc[r];
        }
    }
}

// out[v][c] = norm_dst[v] * sum_{u->v} y[u][c] + b3[c], c < 40. One wave/node.
__global__ __launch_bounds__(256) void agg40_kernel(const float* __restrict__ y,
        const int* __restrict__ row_ptr, const int* __restrict__ col,
        const float* __restrict__ norm_dst, const float* __restrict__ b3,
        float* __restrict__ out, int n) {
    int wid  = (blockIdx.x * blockDim.x + threadIdx.x) >> 6;
    int lane = threadIdx.x & 63;
    if (wid >= n) return;
    int start = row_ptr[wid], end = row_ptr[wid + 1];
    float acc = 0.f;
    for (int b = start; b < end; b += 64) {
        int m = end - b; if (m > 64) m = 64;
        int u = 0;
        if (lane < m) u = col[b + lane];
        for (int j = 0; j < m; ++j) {
            int uu = __shfl(u, j);
            if (lane < 40) acc += y[(size_t)uu * 40 + lane];
        }
    }
    if (lane < 40) out[(size_t)wid * 40 + lane] = norm_dst[wid] * acc + b3[lane];
}

extern "C" void kernel_launch(void* const* d_in, const int* in_sizes, int n_in,
                              void* d_out, int out_size, void* d_ws, size_t ws_size,
                              hipStream_t stream) {
    const float* features = (const float*)d_in[0];
    const int*   ei       = (const int*)d_in[1];
    const float* W1 = (const float*)d_in[2];
    const float* b1 = (const float*)d_in[3];
    const float* W2 = (const float*)d_in[4];
    const float* b2 = (const float*)d_in[5];
    const float* W3 = (const float*)d_in[6];
    const float* b3 = (const float*)d_in[7];

    const int n = in_sizes[0] / 128;
    const int E = in_sizes[1] / 2;

    const int nblk1 = (E + EPB - 1) / EPB;      // partition blocks (196)
    const int NB    = (n + 255) >> 8;           // buckets (196)
    const int L     = NB * nblk1;
    const int L2    = 2 * L;                    // D hist + S hist
    const int sb2   = (L2 + SCAN_CHUNK - 1) / SCAN_CHUNK;

    char* w = (char*)d_ws;
    auto alloc = [&](size_t bytes) {
        char* p = w;
        w += (bytes + 255) & ~(size_t)255;
        return p;
    };
    int*    hist_all = (int*)   alloc((size_t)L2 * 4);
    int*    partials = (int*)   alloc((size_t)256 * 4);
    float*  norm_src = (float*) alloc((size_t)n * 4);
    float*  norm_dst = (float*) alloc((size_t)n * 4);
    int*    row_ptr  = (int*)   alloc((size_t)(n + 1) * 4);
    int*    col      = (int*)   alloc((size_t)E * 4);
    ushort* xb       = (ushort*)alloc((size_t)n * 128 * 2);  // bf16 table; y aliases
    float*  bufA     = (float*) alloc((size_t)n * 128 * 4);  // T1/agg; scratch aliases below

    // CSR-build scratch aliases bufA (consumed before mm1 writes T1=bufA).
    char* scr = (char*)bufA;
    ushort*        rankD = (ushort*)scr;                 scr += ((size_t)E * 2 + 255) & ~(size_t)255;
    ushort*        rankS = (ushort*)scr;                 scr += ((size_t)E * 2 + 255) & ~(size_t)255;
    unsigned*      packD = (unsigned*)scr;               scr += ((size_t)E * 4 + 255) & ~(size_t)255;
    unsigned char* srcb  = (unsigned char*)scr;
    float* T1 = bufA;
    float* y  = (float*)xb;  // y (n*40 fp32) aliases xb; xb2 consumed before y written

    int eb = (E + 255) / 256;  (void)eb;
    int mb = (n + 31) / 32;
    int cb = (n * 32 + 255) / 256;
    int ab = (n + 3) / 4;

    hist_rank_kernel<<<nblk1, 256, 0, stream>>>(ei, E, nblk1, NB, hist_all, rankD, rankS);
    scanA_kernel<<<sb2, 256, 0, stream>>>(hist_all, L2, partials);
    scanB_kernel<<<1, 256, 0, stream>>>(partials, sb2);
    scanC_kernel<<<sb2, 256, 0, stream>>>(hist_all, L2, partials);
    scatter_part_kernel<<<nblk1, 256, 0, stream>>>(ei, E, nblk1, NB, hist_all,
                                                   rankD, rankS, packD, srcb);
    bucket_kernel<<<2 * NB, 256, 0, stream>>>(packD, srcb, hist_all, nblk1, NB, n, E,
                                              row_ptr, col, norm_src, norm_dst);
    mm1_kernel<<<mb, 256, 0, stream>>>(features, W1, T1, n);
    convert_kernel<<<cb, 256, 0, stream>>>(T1, norm_src, xb, n);
    agg128_kernel<<<ab, 256, 0, stream>>>(xb, row_ptr, col, bufA, n);
    mm128_l2_kernel<<<mb, 256, 0, stream>>>(bufA, W2, b1, norm_dst, norm_src, xb, n);
    agg128_kernel<<<ab, 256, 0, stream>>>(xb, row_ptr, col, bufA, n);
    mm40_l3_kernel<<<mb, 256, 0, stream>>>(bufA, W3, b2, norm_dst, norm_src, y, n);
    agg40_kernel<<<ab, 256, 0, stream>>>(y, row_ptr, col, norm_dst, b3, (float*)d_out, n);
}

// Round 11
// 249.026 us; speedup vs baseline: 1.2912x; 1.1240x over previous
//
#include <hip/hip_runtime.h>

// GCN 3-layer forward on MI355X.
// CSR build WITHOUT global atomics (memory-side RMW ceiling ~22G/s measured):
//   hist_rank / scan / scatter_part / bucket  (LDS atomics only)
// Then (segment_sum(M)@W == segment_sum(M@W), matmul before aggregation):
//   mm1: T1 = x@W1; convert: xb = bf16(ns*T1)
//   agg128 -> mm128_l2 (relu/norm fused, bf16 out) -> agg128
//   mm40_l3 -> yb (bf16, rows padded 40->64) -> agg40 (8 edges/iter, uint4)

#define EPB 4096          // edges per partition block (256 threads x 16)
#define SCAN_CHUNK 4096

__device__ __forceinline__ ushort f2bf(float f) {
    unsigned u = __float_as_uint(f);
    unsigned r = (u + 0x7fffu + ((u >> 16) & 1u)) >> 16;  // RN-even
    return (ushort)r;
}
__device__ __forceinline__ void unpack2(unsigned w, float& lo, float& hi) {
    lo = __uint_as_float(w << 16);
    hi = __uint_as_float(w & 0xffff0000u);
}

// Pass 1: per-block LDS histograms (dst>>8, src>>8) + in-block ranks.
__global__ __launch_bounds__(256) void hist_rank_kernel(const int* __restrict__ ei, int E,
        int nblk1, int NB, int* __restrict__ hist_all,
        ushort* __restrict__ rankD, ushort* __restrict__ rankS) {
    __shared__ int hd[512];
    __shared__ int hs[512];
    int t = threadIdx.x, blk = blockIdx.x;
    for (int i = t; i < 512; i += 256) { hd[i] = 0; hs[i] = 0; }
    __syncthreads();
    int base = blk * EPB;
    #pragma unroll
    for (int j = 0; j < 16; ++j) {
        int e = base + j * 256 + t;
        if (e < E) {
            int s = ei[e], d = ei[E + e];
            rankS[e] = (ushort)atomicAdd(&hs[s >> 8], 1);
            rankD[e] = (ushort)atomicAdd(&hd[d >> 8], 1);
        }
    }
    __syncthreads();
    int L = NB * nblk1;
    for (int b = t; b < NB; b += 256) {
        hist_all[b * nblk1 + blk]     = hd[b];
        hist_all[L + b * nblk1 + blk] = hs[b];
    }
}

// Generic hierarchical exclusive scan over data[0..L2)
__global__ __launch_bounds__(256) void scanA_kernel(const int* __restrict__ data, int L2,
                                                    int* __restrict__ partials) {
    __shared__ int red[256];
    int t = threadIdx.x;
    int base = blockIdx.x * SCAN_CHUNK;
    int s = 0;
    for (int i = t; i < SCAN_CHUNK; i += 256) {
        int idx = base + i;
        if (idx < L2) s += data[idx];
    }
    red[t] = s;
    __syncthreads();
    for (int off = 128; off > 0; off >>= 1) {
        if (t < off) red[t] += red[t + off];
        __syncthreads();
    }
    if (t == 0) partials[blockIdx.x] = red[0];
}

__global__ __launch_bounds__(256) void scanB_kernel(int* __restrict__ partials, int nparts) {
    __shared__ int s[256];
    int t = threadIdx.x;
    s[t] = (t < nparts) ? partials[t] : 0;
    __syncthreads();
    for (int off = 1; off < 256; off <<= 1) {
        int v = (t >= off) ? s[t - off] : 0;
        __syncthreads();
        s[t] += v;
        __syncthreads();
    }
    if (t < nparts) partials[t] = s[t] - partials[t];
}

__global__ __launch_bounds__(256) void scanC_kernel(int* __restrict__ data, int L2,
                                                    const int* __restrict__ partials) {
    __shared__ int tsum[256];
    int t = threadIdx.x;
    int base = blockIdx.x * SCAN_CHUNK + t * 16;
    int local[16];
    int s = 0;
    #pragma unroll
    for (int i = 0; i < 16; ++i) {
        int idx = base + i;
        int v = (idx < L2) ? data[idx] : 0;
        local[i] = v;
        s += v;
    }
    tsum[t] = s;
    __syncthreads();
    for (int off = 1; off < 256; off <<= 1) {
        int v = (t >= off) ? tsum[t - off] : 0;
        __syncthreads();
        tsum[t] += v;
        __syncthreads();
    }
    int run = partials[blockIdx.x] + (t ? tsum[t - 1] : 0);
    #pragma unroll
    for (int i = 0; i < 16; ++i) {
        int idx = base + i;
        if (idx < L2) {
            data[idx] = run;
            run += local[i];
        }
    }
}

// Pass 1c: scatter into bucket partitions using scanned bases + stored ranks.
__global__ __launch_bounds__(256) void scatter_part_kernel(const int* __restrict__ ei, int E,
        int nblk1, int NB, const int* __restrict__ hist_all,
        const ushort* __restrict__ rankD, const ushort* __restrict__ rankS,
        unsigned* __restrict__ packD, unsigned char* __restrict__ srcb) {
    int t = threadIdx.x, blk = blockIdx.x;
    int base = blk * EPB;
    int L = NB * nblk1;
    #pragma unroll
    for (int j = 0; j < 16; ++j) {
        int e = base + j * 256 + t;
        if (e < E) {
            int s = ei[e], d = ei[E + e];
            int posD = hist_all[(d >> 8) * nblk1 + blk] + (int)rankD[e];
            packD[posD] = ((unsigned)(d & 255) << 24) | (unsigned)s;
            int posS = hist_all[L + (s >> 8) * nblk1 + blk] - E + (int)rankS[e];
            srcb[posS] = (unsigned char)(s & 255);
        }
    }
}

// Pass 2: blocks [0,NB): dst-bucket -> row_ptr, norm_dst, ranked col placement.
//         blocks [NB,2NB): src-bucket -> norm_src. LDS atomics only.
__global__ __launch_bounds__(256) void bucket_kernel(const unsigned* __restrict__ packD,
        const unsigned char* __restrict__ srcb, const int* __restrict__ hist_all,
        int nblk1, int NB, int n, int E,
        int* __restrict__ row_ptr, int* __restrict__ col,
        float* __restrict__ norm_src, float* __restrict__ norm_dst) {
    int t = threadIdx.x;
    __shared__ int cnt[256];
    __shared__ int incl[256];
    __shared__ int cur[256];
    if ((int)blockIdx.x < NB) {
        int B = blockIdx.x;
        int s0 = hist_all[B * nblk1];
        int s1 = (B + 1 < NB) ? hist_all[(B + 1) * nblk1] : E;
        cnt[t] = 0;
        __syncthreads();
        for (int i = s0 + t; i < s1; i += 256)
            atomicAdd(&cnt[packD[i] >> 24], 1);
        __syncthreads();
        int v = cnt[t];
        incl[t] = v;
        __syncthreads();
        for (int off = 1; off < 256; off <<= 1) {
            int w = (t >= off) ? incl[t - off] : 0;
            __syncthreads();
            incl[t] += w;
            __syncthreads();
        }
        int excl = incl[t] - v;
        cur[t] = excl;
        int node = B * 256 + t;
        if (node < n) {
            row_ptr[node] = s0 + excl;
            norm_dst[node] = rsqrtf((float)(v > 0 ? v : 1));
        }
        if (B == NB - 1 && t == 0) row_ptr[n] = E;
        __syncthreads();
        for (int i = s0 + t; i < s1; i += 256) {
            unsigned p = packD[i];
            int r = atomicAdd(&cur[p >> 24], 1);
            col[s0 + r] = (int)(p & 0xFFFFFFu);
        }
    } else {
        int B = (int)blockIdx.x - NB;
        int L = NB * nblk1;
        int s0 = hist_all[L + B * nblk1] - E;
        int s1 = (B + 1 < NB) ? (hist_all[L + (B + 1) * nblk1] - E) : E;
        cnt[t] = 0;
        __syncthreads();
        for (int i = s0 + t; i < s1; i += 256)
            atomicAdd(&cnt[srcb[i]], 1);
        __syncthreads();
        int node = B * 256 + t;
        if (node < n) {
            int v = cnt[t];
            norm_src[node] = rsqrtf((float)(v > 0 ? v : 1));
        }
    }
}

// T1 = x @ W1 (raw fp32). 32-row tiles; W1 streamed from L2.
__global__ __launch_bounds__(256, 4) void mm1_kernel(const float* __restrict__ x,
        const float* __restrict__ W1, float* __restrict__ T1, int n) {
    __shared__ float Xl[32][128];
    int t = threadIdx.x;
    int row0 = blockIdx.x * 32;
    for (int i = t; i < 32 * 32; i += 256) {
        int r = i >> 5, k4 = i & 31;
        int gr = row0 + r;
        float4 xv = make_float4(0.f, 0.f, 0.f, 0.f);
        if (gr < n) xv = reinterpret_cast<const float4*>(x)[(size_t)gr * 32 + k4];
        reinterpret_cast<float4*>(&Xl[r][0])[k4] = xv;
    }
    __syncthreads();
    int wv = t >> 6, lane = t & 63;
    int c0 = lane, c1 = lane + 64;
    float acc0[8], acc1[8];
    #pragma unroll
    for (int r = 0; r < 8; ++r) { acc0[r] = 0.f; acc1[r] = 0.f; }
    int rbase = wv * 8;
    const float* Wp0 = W1 + c0;
    const float* Wp1 = W1 + c1;
    for (int k = 0; k < 128; k += 4) {
        float w00 = Wp0[(k + 0) * 128], w10 = Wp1[(k + 0) * 128];
        float w01 = Wp0[(k + 1) * 128], w11 = Wp1[(k + 1) * 128];
        float w02 = Wp0[(k + 2) * 128], w12 = Wp1[(k + 2) * 128];
        float w03 = Wp0[(k + 3) * 128], w13 = Wp1[(k + 3) * 128];
        #pragma unroll
        for (int r = 0; r < 8; ++r) {
            float4 xv = *reinterpret_cast<const float4*>(&Xl[rbase + r][k]);
            acc0[r] = fmaf(xv.x, w00, acc0[r]);
            acc1[r] = fmaf(xv.x, w10, acc1[r]);
            acc0[r] = fmaf(xv.y, w01, acc0[r]);
            acc1[r] = fmaf(xv.y, w11, acc1[r]);
            acc0[r] = fmaf(xv.z, w02, acc0[r]);
            acc1[r] = fmaf(xv.z, w12, acc1[r]);
            acc0[r] = fmaf(xv.w, w03, acc0[r]);
            acc1[r] = fmaf(xv.w, w13, acc1[r]);
        }
    }
    #pragma unroll
    for (int r = 0; r < 8; ++r) {
        int gr = row0 + rbase + r;
        if (gr < n) {
            T1[(size_t)gr * 128 + c0] = acc0[r];
            T1[(size_t)gr * 128 + c1] = acc1[r];
        }
    }
}

// xb = bf16(ns * T1)
__global__ __launch_bounds__(256) void convert_kernel(const float* __restrict__ T1,
        const float* __restrict__ ns, ushort* __restrict__ xb, int n) {
    int i = blockIdx.x * blockDim.x + threadIdx.x;
    if (i >= n * 32) return;
    int row = i >> 5;
    float s = ns[row];
    float4 v = reinterpret_cast<const float4*>(T1)[i];
    ushort4 o;
    o.x = f2bf(v.x * s); o.y = f2bf(v.y * s);
    o.z = f2bf(v.z * s); o.w = f2bf(v.w * s);
    reinterpret_cast<ushort4*>(xb)[i] = o;
}

// One wave per node: out[v][:] = sum_{u->v} xb[u][:] (bf16 rows, fp32 accum).
__global__ __launch_bounds__(256) void agg128_kernel(const ushort* __restrict__ xb,
        const int* __restrict__ row_ptr, const int* __restrict__ col,
        float* __restrict__ out, int n) {
    int wid  = (blockIdx.x * blockDim.x + threadIdx.x) >> 6;
    int lane = threadIdx.x & 63;
    if (wid >= n) return;
    int start = row_ptr[wid], end = row_ptr[wid + 1];
    int quarter = lane >> 4, l4 = lane & 15;
    float acc[8];
    #pragma unroll
    for (int i = 0; i < 8; ++i) acc[i] = 0.f;
    for (int b = start; b < end; b += 64) {
        int m = end - b; if (m > 64) m = 64;
        int u = 0;
        if (lane < m) u = col[b + lane];
        for (int j = 0; j < m; j += 4) {
            int jj = j + quarter;
            int uu = __shfl(u, jj);
            if (jj < m) {
                const uint4 v = *reinterpret_cast<const uint4*>(xb + (size_t)uu * 128 + 8 * l4);
                float f0, f1;
                unpack2(v.x, f0, f1); acc[0] += f0; acc[1] += f1;
                unpack2(v.y, f0, f1); acc[2] += f0; acc[3] += f1;
                unpack2(v.z, f0, f1); acc[4] += f0; acc[5] += f1;
                unpack2(v.w, f0, f1); acc[6] += f0; acc[7] += f1;
            }
        }
    }
    #pragma unroll
    for (int i = 0; i < 8; ++i) {
        acc[i] += __shfl_xor(acc[i], 16);
        acc[i] += __shfl_xor(acc[i], 32);
    }
    if (lane < 16) {
        float* op = out + (size_t)wid * 128 + 8 * lane;
        *reinterpret_cast<float4*>(op)     = make_float4(acc[0], acc[1], acc[2], acc[3]);
        *reinterpret_cast<float4*>(op + 4) = make_float4(acc[4], acc[5], acc[6], acc[7]);
    }
}

// Layer 2: X' = relu(nd*agg1 + b1) at LDS-load; out = bf16(ns * (X'@W2)).
__global__ __launch_bounds__(256, 4) void mm128_l2_kernel(const float* __restrict__ agg,
        const float* __restrict__ W2, const float* __restrict__ b1,
        const float* __restrict__ norm_dst, const float* __restrict__ norm_src,
        ushort* __restrict__ out, int n) {
    __shared__ float Xl[32][128];
    int t = threadIdx.x;
    int row0 = blockIdx.x * 32;
    for (int i = t; i < 32 * 32; i += 256) {
        int r = i >> 5, k4 = i & 31;
        int gr = row0 + r;
        float4 xv = make_float4(0.f, 0.f, 0.f, 0.f);
        if (gr < n) {
            xv = reinterpret_cast<const float4*>(agg)[(size_t)gr * 32 + k4];
            float4 bb = reinterpret_cast<const float4*>(b1)[k4];
            float nd = norm_dst[gr];
            xv.x = fmaxf(fmaf(nd, xv.x, bb.x), 0.f);
            xv.y = fmaxf(fmaf(nd, xv.y, bb.y), 0.f);
            xv.z = fmaxf(fmaf(nd, xv.z, bb.z), 0.f);
            xv.w = fmaxf(fmaf(nd, xv.w, bb.w), 0.f);
        }
        reinterpret_cast<float4*>(&Xl[r][0])[k4] = xv;
    }
    __syncthreads();
    int wv = t >> 6, lane = t & 63;
    int c0 = lane, c1 = lane + 64;
    float acc0[8], acc1[8];
    #pragma unroll
    for (int r = 0; r < 8; ++r) { acc0[r] = 0.f; acc1[r] = 0.f; }
    int rbase = wv * 8;
    const float* Wp0 = W2 + c0;
    const float* Wp1 = W2 + c1;
    for (int k = 0; k < 128; k += 4) {
        float w00 = Wp0[(k + 0) * 128], w10 = Wp1[(k + 0) * 128];
        float w01 = Wp0[(k + 1) * 128], w11 = Wp1[(k + 1) * 128];
        float w02 = Wp0[(k + 2) * 128], w12 = Wp1[(k + 2) * 128];
        float w03 = Wp0[(k + 3) * 128], w13 = Wp1[(k + 3) * 128];
        #pragma unroll
        for (int r = 0; r < 8; ++r) {
            float4 xv = *reinterpret_cast<const float4*>(&Xl[rbase + r][k]);
            acc0[r] = fmaf(xv.x, w00, acc0[r]);
            acc1[r] = fmaf(xv.x, w10, acc1[r]);
            acc0[r] = fmaf(xv.y, w01, acc0[r]);
            acc1[r] = fmaf(xv.y, w11, acc1[r]);
            acc0[r] = fmaf(xv.z, w02, acc0[r]);
            acc1[r] = fmaf(xv.z, w12, acc1[r]);
            acc0[r] = fmaf(xv.w, w03, acc0[r]);
            acc1[r] = fmaf(xv.w, w13, acc1[r]);
        }
    }
    #pragma unroll
    for (int r = 0; r < 8; ++r) {
        int gr = row0 + rbase + r;
        if (gr < n) {
            float ns = norm_src[gr];
            out[(size_t)gr * 128 + c0] = f2bf(ns * acc0[r]);
            out[(size_t)gr * 128 + c1] = f2bf(ns * acc1[r]);
        }
    }
}

// Layer 3 mm: X'' = ns*relu(nd*agg2 + b2) at load; yb = bf16(X''@W3),
// rows padded 40 -> 64 bf16 (zeros) for 16B-aligned gather in agg40.
__global__ __launch_bounds__(256, 4) void mm40_l3_kernel(const float* __restrict__ agg,
        const float* __restrict__ W3, const float* __restrict__ b2,
        const float* __restrict__ norm_dst, const float* __restrict__ norm_src,
        ushort* __restrict__ yb, int n) {
    __shared__ float Xl[32][128];
    int t = threadIdx.x;
    int row0 = blockIdx.x * 32;
    for (int i = t; i < 32 * 32; i += 256) {
        int r = i >> 5, k4 = i & 31;
        int gr = row0 + r;
        float4 xv = make_float4(0.f, 0.f, 0.f, 0.f);
        if (gr < n) {
            xv = reinterpret_cast<const float4*>(agg)[(size_t)gr * 32 + k4];
            float4 bb = reinterpret_cast<const float4*>(b2)[k4];
            float nd = norm_dst[gr], ns = norm_src[gr];
            xv.x = ns * fmaxf(fmaf(nd, xv.x, bb.x), 0.f);
            xv.y = ns * fmaxf(fmaf(nd, xv.y, bb.y), 0.f);
            xv.z = ns * fmaxf(fmaf(nd, xv.z, bb.z), 0.f);
            xv.w = ns * fmaxf(fmaf(nd, xv.w, bb.w), 0.f);
        }
        reinterpret_cast<float4*>(&Xl[r][0])[k4] = xv;
    }
    __syncthreads();
    int wv = t >> 6, lane = t & 63;
    int c = (lane < 40) ? lane : 0;
    float acc[8];
    #pragma unroll
    for (int r = 0; r < 8; ++r) acc[r] = 0.f;
    int rbase = wv * 8;
    const float* Wp = W3 + c;
    for (int k = 0; k < 128; k += 2) {
        float w0 = Wp[(k + 0) * 40];
        float w1 = Wp[(k + 1) * 40];
        #pragma unroll
        for (int r = 0; r < 8; ++r) {
            float2 xv = *reinterpret_cast<const float2*>(&Xl[rbase + r][k]);
            acc[r] = fmaf(xv.x, w0, acc[r]);
            acc[r] = fmaf(xv.y, w1, acc[r]);
        }
    }
    #pragma unroll
    for (int r = 0; r < 8; ++r) {
        int gr = row0 + rbase + r;
        if (gr < n)
            yb[(size_t)gr * 64 + lane] = (lane < 40) ? f2bf(acc[r]) : (ushort)0;
    }
}

// out[v][c] = norm_dst[v] * sum_{u->v} yb[u][c] + b3[c], c < 40.
// One wave/node, 8 edges/iter: octant=lane>>3 picks edge, l8=lane&7 loads
// uint4 (8 bf16 dims). Octant shfl_xor reduce; lanes l8<5 write 8 floats.
__global__ __launch_bounds__(256) void agg40_kernel(const ushort* __restrict__ yb,
        const int* __restrict__ row_ptr, const int* __restrict__ col,
        const float* __restrict__ norm_dst, const float* __restrict__ b3,
        float* __restrict__ out, int n) {
    int wid  = (blockIdx.x * blockDim.x + threadIdx.x) >> 6;
    int lane = threadIdx.x & 63;
    if (wid >= n) return;
    int start = row_ptr[wid], end = row_ptr[wid + 1];
    int oct = lane >> 3, l8 = lane & 7;
    float acc[8];
    #pragma unroll
    for (int i = 0; i < 8; ++i) acc[i] = 0.f;
    for (int b = start; b < end; b += 64) {
        int m = end - b; if (m > 64) m = 64;
        int u = 0;
        if (lane < m) u = col[b + lane];
        for (int j = 0; j < m; j += 8) {
            int jj = j + oct;
            int uu = __shfl(u, jj);
            if (jj < m) {
                const uint4 v = *reinterpret_cast<const uint4*>(yb + (size_t)uu * 64 + 8 * l8);
                float f0, f1;
                unpack2(v.x, f0, f1); acc[0] += f0; acc[1] += f1;
                unpack2(v.y, f0, f1); acc[2] += f0; acc[3] += f1;
                unpack2(v.z, f0, f1); acc[4] += f0; acc[5] += f1;
                unpack2(v.w, f0, f1); acc[6] += f0; acc[7] += f1;
            }
        }
    }
    #pragma unroll
    for (int i = 0; i < 8; ++i) {
        acc[i] += __shfl_xor(acc[i], 8);
        acc[i] += __shfl_xor(acc[i], 16);
        acc[i] += __shfl_xor(acc[i], 32);
    }
    if (lane < 5) {  // oct==0, l8 0..4 -> dims l8*8 .. l8*8+7 (40 total)
        float nd = norm_dst[wid];
        const float* bp = b3 + 8 * lane;
        float* op = out + (size_t)wid * 40 + 8 * lane;
        float4 o0, o1;
        o0.x = fmaf(nd, acc[0], bp[0]); o0.y = fmaf(nd, acc[1], bp[1]);
        o0.z = fmaf(nd, acc[2], bp[2]); o0.w = fmaf(nd, acc[3], bp[3]);
        o1.x = fmaf(nd, acc[4], bp[4]); o1.y = fmaf(nd, acc[5], bp[5]);
        o1.z = fmaf(nd, acc[6], bp[6]); o1.w = fmaf(nd, acc[7], bp[7]);
        *reinterpret_cast<float4*>(op)     = o0;
        *reinterpret_cast<float4*>(op + 4) = o1;
    }
}

extern "C" void kernel_launch(void* const* d_in, const int* in_sizes, int n_in,
                              void* d_out, int out_size, void* d_ws, size_t ws_size,
                              hipStream_t stream) {
    const float* features = (const float*)d_in[0];
    const int*   ei       = (const int*)d_in[1];
    const float* W1 = (const float*)d_in[2];
    const float* b1 = (const float*)d_in[3];
    const float* W2 = (const float*)d_in[4];
    const float* b2 = (const float*)d_in[5];
    const float* W3 = (const float*)d_in[6];
    const float* b3 = (const float*)d_in[7];

    const int n = in_sizes[0] / 128;
    const int E = in_sizes[1] / 2;

    const int nblk1 = (E + EPB - 1) / EPB;      // partition blocks (196)
    const int NB    = (n + 255) >> 8;           // buckets (196)
    const int L     = NB * nblk1;
    const int L2    = 2 * L;                    // D hist + S hist
    const int sb2   = (L2 + SCAN_CHUNK - 1) / SCAN_CHUNK;

    char* w = (char*)d_ws;
    auto alloc = [&](size_t bytes) {
        char* p = w;
        w += (bytes + 255) & ~(size_t)255;
        return p;
    };
    int*    hist_all = (int*)   alloc((size_t)L2 * 4);
    int*    partials = (int*)   alloc((size_t)256 * 4);
    float*  norm_src = (float*) alloc((size_t)n * 4);
    float*  norm_dst = (float*) alloc((size_t)n * 4);
    int*    row_ptr  = (int*)   alloc((size_t)(n + 1) * 4);
    int*    col      = (int*)   alloc((size_t)E * 4);
    ushort* xb       = (ushort*)alloc((size_t)n * 128 * 2);  // bf16 table; yb aliases
    float*  bufA     = (float*) alloc((size_t)n * 128 * 4);  // T1/agg; scratch aliases below

    // CSR-build scratch aliases bufA (consumed before mm1 writes T1=bufA).
    char* scr = (char*)bufA;
    ushort*        rankD = (ushort*)scr;                 scr += ((size_t)E * 2 + 255) & ~(size_t)255;
    ushort*        rankS = (ushort*)scr;                 scr += ((size_t)E * 2 + 255) & ~(size_t)255;
    unsigned*      packD = (unsigned*)scr;               scr += ((size_t)E * 4 + 255) & ~(size_t)255;
    unsigned char* srcb  = (unsigned char*)scr;
    float*  T1 = bufA;
    ushort* yb = xb;   // yb (n*64 bf16 = 6.4MB) aliases xb (12.8MB); xb2 consumed
                       // by agg128 #2 before mm40_l3 writes yb

    int mb = (n + 31) / 32;
    int cb = (n * 32 + 255) / 256;
    int ab = (n + 3) / 4;

    hist_rank_kernel<<<nblk1, 256, 0, stream>>>(ei, E, nblk1, NB, hist_all, rankD, rankS);
    scanA_kernel<<<sb2, 256, 0, stream>>>(hist_all, L2, partials);
    scanB_kernel<<<1, 256, 0, stream>>>(partials, sb2);
    scanC_kernel<<<sb2, 256, 0, stream>>>(hist_all, L2, partials);
    scatter_part_kernel<<<nblk1, 256, 0, stream>>>(ei, E, nblk1, NB, hist_all,
                                                   rankD, rankS, packD, srcb);
    bucket_kernel<<<2 * NB, 256, 0, stream>>>(packD, srcb, hist_all, nblk1, NB, n, E,
                                              row_ptr, col, norm_src, norm_dst);
    mm1_kernel<<<mb, 256, 0, stream>>>(features, W1, T1, n);
    convert_kernel<<<cb, 256, 0, stream>>>(T1, norm_src, xb, n);
    agg128_kernel<<<ab, 256, 0, stream>>>(xb, row_ptr, col, bufA, n);
    mm128_l2_kernel<<<mb, 256, 0, stream>>>(bufA, W2, b1, norm_dst, norm_src, xb, n);
    agg128_kernel<<<ab, 256, 0, stream>>>(xb, row_ptr, col, bufA, n);
    mm40_l3_kernel<<<mb, 256, 0, stream>>>(bufA, W3, b2, norm_dst, norm_src, yb, n);
    agg40_kernel<<<ab, 256, 0, stream>>>(yb, row_ptr, col, norm_dst, b3, (float*)d_out, n);
}

// Round 12
// 241.193 us; speedup vs baseline: 1.3331x; 1.0325x over previous
//
#include <hip/hip_runtime.h>

// GCN 3-layer forward on MI355X.
// CSR build WITHOUT global atomics (memory-side RMW ceiling ~22G/s measured):
//   hist_rank / scan / scatter_part / bucket  (LDS atomics only)
// Then (segment_sum(M)@W == segment_sum(M@W), matmul before aggregation):
//   mm1: xb = bf16(ns*(x@W1))  (convert fused into epilogue)
//   agg128 -> mm128_l2 (relu/norm fused, bf16 out) -> agg128
//   mm40_l3 -> yb (bf16, rows padded 40->64) -> agg40 (8 edges/iter, uint4)
// mm kernels: 16-row tiles (3125 blocks), col-split waves (1 col/lane),
// __launch_bounds__(256,8) for 32-wave/CU latency hiding.

#define EPB 4096          // edges per partition block (256 threads x 16)
#define SCAN_CHUNK 4096

__device__ __forceinline__ ushort f2bf(float f) {
    unsigned u = __float_as_uint(f);
    unsigned r = (u + 0x7fffu + ((u >> 16) & 1u)) >> 16;  // RN-even
    return (ushort)r;
}
__device__ __forceinline__ void unpack2(unsigned w, float& lo, float& hi) {
    lo = __uint_as_float(w << 16);
    hi = __uint_as_float(w & 0xffff0000u);
}

// Pass 1: per-block LDS histograms (dst>>8, src>>8) + in-block ranks.
__global__ __launch_bounds__(256) void hist_rank_kernel(const int* __restrict__ ei, int E,
        int nblk1, int NB, int* __restrict__ hist_all,
        ushort* __restrict__ rankD, ushort* __restrict__ rankS) {
    __shared__ int hd[512];
    __shared__ int hs[512];
    int t = threadIdx.x, blk = blockIdx.x;
    for (int i = t; i < 512; i += 256) { hd[i] = 0; hs[i] = 0; }
    __syncthreads();
    int base = blk * EPB;
    #pragma unroll
    for (int j = 0; j < 16; ++j) {
        int e = base + j * 256 + t;
        if (e < E) {
            int s = ei[e], d = ei[E + e];
            rankS[e] = (ushort)atomicAdd(&hs[s >> 8], 1);
            rankD[e] = (ushort)atomicAdd(&hd[d >> 8], 1);
        }
    }
    __syncthreads();
    int L = NB * nblk1;
    for (int b = t; b < NB; b += 256) {
        hist_all[b * nblk1 + blk]     = hd[b];
        hist_all[L + b * nblk1 + blk] = hs[b];
    }
}

// Generic hierarchical exclusive scan over data[0..L2)
__global__ __launch_bounds__(256) void scanA_kernel(const int* __restrict__ data, int L2,
                                                    int* __restrict__ partials) {
    __shared__ int red[256];
    int t = threadIdx.x;
    int base = blockIdx.x * SCAN_CHUNK;
    int s = 0;
    for (int i = t; i < SCAN_CHUNK; i += 256) {
        int idx = base + i;
        if (idx < L2) s += data[idx];
    }
    red[t] = s;
    __syncthreads();
    for (int off = 128; off > 0; off >>= 1) {
        if (t < off) red[t] += red[t + off];
        __syncthreads();
    }
    if (t == 0) partials[blockIdx.x] = red[0];
}

__global__ __launch_bounds__(256) void scanB_kernel(int* __restrict__ partials, int nparts) {
    __shared__ int s[256];
    int t = threadIdx.x;
    s[t] = (t < nparts) ? partials[t] : 0;
    __syncthreads();
    for (int off = 1; off < 256; off <<= 1) {
        int v = (t >= off) ? s[t - off] : 0;
        __syncthreads();
        s[t] += v;
        __syncthreads();
    }
    if (t < nparts) partials[t] = s[t] - partials[t];
}

__global__ __launch_bounds__(256) void scanC_kernel(int* __restrict__ data, int L2,
                                                    const int* __restrict__ partials) {
    __shared__ int tsum[256];
    int t = threadIdx.x;
    int base = blockIdx.x * SCAN_CHUNK + t * 16;
    int local[16];
    int s = 0;
    #pragma unroll
    for (int i = 0; i < 16; ++i) {
        int idx = base + i;
        int v = (idx < L2) ? data[idx] : 0;
        local[i] = v;
        s += v;
    }
    tsum[t] = s;
    __syncthreads();
    for (int off = 1; off < 256; off <<= 1) {
        int v = (t >= off) ? tsum[t - off] : 0;
        __syncthreads();
        tsum[t] += v;
        __syncthreads();
    }
    int run = partials[blockIdx.x] + (t ? tsum[t - 1] : 0);
    #pragma unroll
    for (int i = 0; i < 16; ++i) {
        int idx = base + i;
        if (idx < L2) {
            data[idx] = run;
            run += local[i];
        }
    }
}

// Pass 1c: scatter into bucket partitions using scanned bases + stored ranks.
__global__ __launch_bounds__(256) void scatter_part_kernel(const int* __restrict__ ei, int E,
        int nblk1, int NB, const int* __restrict__ hist_all,
        const ushort* __restrict__ rankD, const ushort* __restrict__ rankS,
        unsigned* __restrict__ packD, unsigned char* __restrict__ srcb) {
    int t = threadIdx.x, blk = blockIdx.x;
    int base = blk * EPB;
    int L = NB * nblk1;
    #pragma unroll
    for (int j = 0; j < 16; ++j) {
        int e = base + j * 256 + t;
        if (e < E) {
            int s = ei[e], d = ei[E + e];
            int posD = hist_all[(d >> 8) * nblk1 + blk] + (int)rankD[e];
            packD[posD] = ((unsigned)(d & 255) << 24) | (unsigned)s;
            int posS = hist_all[L + (s >> 8) * nblk1 + blk] - E + (int)rankS[e];
            srcb[posS] = (unsigned char)(s & 255);
        }
    }
}

// Pass 2: blocks [0,NB): dst-bucket -> row_ptr, norm_dst, ranked col placement.
//         blocks [NB,2NB): src-bucket -> norm_src. LDS atomics only.
__global__ __launch_bounds__(256) void bucket_kernel(const unsigned* __restrict__ packD,
        const unsigned char* __restrict__ srcb, const int* __restrict__ hist_all,
        int nblk1, int NB, int n, int E,
        int* __restrict__ row_ptr, int* __restrict__ col,
        float* __restrict__ norm_src, float* __restrict__ norm_dst) {
    int t = threadIdx.x;
    __shared__ int cnt[256];
    __shared__ int incl[256];
    __shared__ int cur[256];
    if ((int)blockIdx.x < NB) {
        int B = blockIdx.x;
        int s0 = hist_all[B * nblk1];
        int s1 = (B + 1 < NB) ? hist_all[(B + 1) * nblk1] : E;
        cnt[t] = 0;
        __syncthreads();
        for (int i = s0 + t; i < s1; i += 256)
            atomicAdd(&cnt[packD[i] >> 24], 1);
        __syncthreads();
        int v = cnt[t];
        incl[t] = v;
        __syncthreads();
        for (int off = 1; off < 256; off <<= 1) {
            int w = (t >= off) ? incl[t - off] : 0;
            __syncthreads();
            incl[t] += w;
            __syncthreads();
        }
        int excl = incl[t] - v;
        cur[t] = excl;
        int node = B * 256 + t;
        if (node < n) {
            row_ptr[node] = s0 + excl;
            norm_dst[node] = rsqrtf((float)(v > 0 ? v : 1));
        }
        if (B == NB - 1 && t == 0) row_ptr[n] = E;
        __syncthreads();
        for (int i = s0 + t; i < s1; i += 256) {
            unsigned p = packD[i];
            int r = atomicAdd(&cur[p >> 24], 1);
            col[s0 + r] = (int)(p & 0xFFFFFFu);
        }
    } else {
        int B = (int)blockIdx.x - NB;
        int L = NB * nblk1;
        int s0 = hist_all[L + B * nblk1] - E;
        int s1 = (B + 1 < NB) ? (hist_all[L + (B + 1) * nblk1] - E) : E;
        cnt[t] = 0;
        __syncthreads();
        for (int i = s0 + t; i < s1; i += 256)
            atomicAdd(&cnt[srcb[i]], 1);
        __syncthreads();
        int node = B * 256 + t;
        if (node < n) {
            int v = cnt[t];
            norm_src[node] = rsqrtf((float)(v > 0 ? v : 1));
        }
    }
}

// mm1: xb[r][c] = bf16( ns[r] * (x[r][:] @ W1[:,c]) ). 16-row tiles,
// col-split waves: wave w -> rows (w&1)*8..+7, col (w>>1)*64 + lane.
__global__ __launch_bounds__(256, 8) void mm1_kernel(const float* __restrict__ x,
        const float* __restrict__ W1, const float* __restrict__ ns,
        ushort* __restrict__ xb, int n) {
    __shared__ float Xl[16][128];
    int t = threadIdx.x;
    int row0 = blockIdx.x * 16;
    for (int i = t; i < 16 * 32; i += 256) {
        int r = i >> 5, k4 = i & 31;
        int gr = row0 + r;
        float4 xv = make_float4(0.f, 0.f, 0.f, 0.f);
        if (gr < n) xv = reinterpret_cast<const float4*>(x)[(size_t)gr * 32 + k4];
        reinterpret_cast<float4*>(&Xl[r][0])[k4] = xv;
    }
    __syncthreads();
    int wv = t >> 6, lane = t & 63;
    int rbase = (wv & 1) * 8;
    int c = ((wv >> 1) << 6) + lane;
    float acc[8];
    #pragma unroll
    for (int r = 0; r < 8; ++r) acc[r] = 0.f;
    const float* Wp = W1 + c;
    for (int k = 0; k < 128; k += 4) {
        float w0 = Wp[(k + 0) * 128];
        float w1 = Wp[(k + 1) * 128];
        float w2 = Wp[(k + 2) * 128];
        float w3 = Wp[(k + 3) * 128];
        #pragma unroll
        for (int r = 0; r < 8; ++r) {
            float4 xv = *reinterpret_cast<const float4*>(&Xl[rbase + r][k]);
            acc[r] = fmaf(xv.x, w0, acc[r]);
            acc[r] = fmaf(xv.y, w1, acc[r]);
            acc[r] = fmaf(xv.z, w2, acc[r]);
            acc[r] = fmaf(xv.w, w3, acc[r]);
        }
    }
    #pragma unroll
    for (int r = 0; r < 8; ++r) {
        int gr = row0 + rbase + r;
        if (gr < n) xb[(size_t)gr * 128 + c] = f2bf(ns[gr] * acc[r]);
    }
}

// One wave per node: out[v][:] = sum_{u->v} xb[u][:] (bf16 rows, fp32 accum).
__global__ __launch_bounds__(256) void agg128_kernel(const ushort* __restrict__ xb,
        const int* __restrict__ row_ptr, const int* __restrict__ col,
        float* __restrict__ out, int n) {
    int wid  = (blockIdx.x * blockDim.x + threadIdx.x) >> 6;
    int lane = threadIdx.x & 63;
    if (wid >= n) return;
    int start = row_ptr[wid], end = row_ptr[wid + 1];
    int quarter = lane >> 4, l4 = lane & 15;
    float acc[8];
    #pragma unroll
    for (int i = 0; i < 8; ++i) acc[i] = 0.f;
    for (int b = start; b < end; b += 64) {
        int m = end - b; if (m > 64) m = 64;
        int u = 0;
        if (lane < m) u = col[b + lane];
        for (int j = 0; j < m; j += 4) {
            int jj = j + quarter;
            int uu = __shfl(u, jj);
            if (jj < m) {
                const uint4 v = *reinterpret_cast<const uint4*>(xb + (size_t)uu * 128 + 8 * l4);
                float f0, f1;
                unpack2(v.x, f0, f1); acc[0] += f0; acc[1] += f1;
                unpack2(v.y, f0, f1); acc[2] += f0; acc[3] += f1;
                unpack2(v.z, f0, f1); acc[4] += f0; acc[5] += f1;
                unpack2(v.w, f0, f1); acc[6] += f0; acc[7] += f1;
            }
        }
    }
    #pragma unroll
    for (int i = 0; i < 8; ++i) {
        acc[i] += __shfl_xor(acc[i], 16);
        acc[i] += __shfl_xor(acc[i], 32);
    }
    if (lane < 16) {
        float* op = out + (size_t)wid * 128 + 8 * lane;
        *reinterpret_cast<float4*>(op)     = make_float4(acc[0], acc[1], acc[2], acc[3]);
        *reinterpret_cast<float4*>(op + 4) = make_float4(acc[4], acc[5], acc[6], acc[7]);
    }
}

// Layer 2: X' = relu(nd*agg + b1) at LDS-load; out = bf16(ns * (X'@W2)).
// Same 16-row col-split structure as mm1.
__global__ __launch_bounds__(256, 8) void mm128_l2_kernel(const float* __restrict__ agg,
        const float* __restrict__ W2, const float* __restrict__ b1,
        const float* __restrict__ norm_dst, const float* __restrict__ norm_src,
        ushort* __restrict__ out, int n) {
    __shared__ float Xl[16][128];
    int t = threadIdx.x;
    int row0 = blockIdx.x * 16;
    for (int i = t; i < 16 * 32; i += 256) {
        int r = i >> 5, k4 = i & 31;
        int gr = row0 + r;
        float4 xv = make_float4(0.f, 0.f, 0.f, 0.f);
        if (gr < n) {
            xv = reinterpret_cast<const float4*>(agg)[(size_t)gr * 32 + k4];
            float4 bb = reinterpret_cast<const float4*>(b1)[k4];
            float nd = norm_dst[gr];
            xv.x = fmaxf(fmaf(nd, xv.x, bb.x), 0.f);
            xv.y = fmaxf(fmaf(nd, xv.y, bb.y), 0.f);
            xv.z = fmaxf(fmaf(nd, xv.z, bb.z), 0.f);
            xv.w = fmaxf(fmaf(nd, xv.w, bb.w), 0.f);
        }
        reinterpret_cast<float4*>(&Xl[r][0])[k4] = xv;
    }
    __syncthreads();
    int wv = t >> 6, lane = t & 63;
    int rbase = (wv & 1) * 8;
    int c = ((wv >> 1) << 6) + lane;
    float acc[8];
    #pragma unroll
    for (int r = 0; r < 8; ++r) acc[r] = 0.f;
    const float* Wp = W2 + c;
    for (int k = 0; k < 128; k += 4) {
        float w0 = Wp[(k + 0) * 128];
        float w1 = Wp[(k + 1) * 128];
        float w2 = Wp[(k + 2) * 128];
        float w3 = Wp[(k + 3) * 128];
        #pragma unroll
        for (int r = 0; r < 8; ++r) {
            float4 xv = *reinterpret_cast<const float4*>(&Xl[rbase + r][k]);
            acc[r] = fmaf(xv.x, w0, acc[r]);
            acc[r] = fmaf(xv.y, w1, acc[r]);
            acc[r] = fmaf(xv.z, w2, acc[r]);
            acc[r] = fmaf(xv.w, w3, acc[r]);
        }
    }
    #pragma unroll
    for (int r = 0; r < 8; ++r) {
        int gr = row0 + rbase + r;
        if (gr < n) out[(size_t)gr * 128 + c] = f2bf(norm_src[gr] * acc[r]);
    }
}

// Layer 3 mm: X'' = ns*relu(nd*agg + b2) at load; yb = bf16(X''@W3),
// rows padded 40 -> 64 bf16 (zeros). 16-row tiles, wave -> 4 rows.
__global__ __launch_bounds__(256, 8) void mm40_l3_kernel(const float* __restrict__ agg,
        const float* __restrict__ W3, const float* __restrict__ b2,
        const float* __restrict__ norm_dst, const float* __restrict__ norm_src,
        ushort* __restrict__ yb, int n) {
    __shared__ float Xl[16][128];
    int t = threadIdx.x;
    int row0 = blockIdx.x * 16;
    for (int i = t; i < 16 * 32; i += 256) {
        int r = i >> 5, k4 = i & 31;
        int gr = row0 + r;
        float4 xv = make_float4(0.f, 0.f, 0.f, 0.f);
        if (gr < n) {
            xv = reinterpret_cast<const float4*>(agg)[(size_t)gr * 32 + k4];
            float4 bb = reinterpret_cast<const float4*>(b2)[k4];
            float nd = norm_dst[gr], ns = norm_src[gr];
            xv.x = ns * fmaxf(fmaf(nd, xv.x, bb.x), 0.f);
            xv.y = ns * fmaxf(fmaf(nd, xv.y, bb.y), 0.f);
            xv.z = ns * fmaxf(fmaf(nd, xv.z, bb.z), 0.f);
            xv.w = ns * fmaxf(fmaf(nd, xv.w, bb.w), 0.f);
        }
        reinterpret_cast<float4*>(&Xl[r][0])[k4] = xv;
    }
    __syncthreads();
    int wv = t >> 6, lane = t & 63;
    int c = (lane < 40) ? lane : 0;
    float acc[4];
    #pragma unroll
    for (int r = 0; r < 4; ++r) acc[r] = 0.f;
    int rbase = wv * 4;
    const float* Wp = W3 + c;
    for (int k = 0; k < 128; k += 2) {
        float w0 = Wp[(k + 0) * 40];
        float w1 = Wp[(k + 1) * 40];
        #pragma unroll
        for (int r = 0; r < 4; ++r) {
            float2 xv = *reinterpret_cast<const float2*>(&Xl[rbase + r][k]);
            acc[r] = fmaf(xv.x, w0, acc[r]);
            acc[r] = fmaf(xv.y, w1, acc[r]);
        }
    }
    #pragma unroll
    for (int r = 0; r < 4; ++r) {
        int gr = row0 + rbase + r;
        if (gr < n)
            yb[(size_t)gr * 64 + lane] = (lane < 40) ? f2bf(acc[r]) : (ushort)0;
    }
}

// out[v][c] = norm_dst[v] * sum_{u->v} yb[u][c] + b3[c], c < 40.
// One wave/node, 8 edges/iter: octant=lane>>3 picks edge, l8=lane&7 loads
// uint4 (8 bf16 dims). Octant shfl_xor reduce; lanes l8<5 write 8 floats.
__global__ __launch_bounds__(256) void agg40_kernel(const ushort* __restrict__ yb,
        const int* __restrict__ row_ptr, const int* __restrict__ col,
        const float* __restrict__ norm_dst, const float* __restrict__ b3,
        float* __restrict__ out, int n) {
    int wid  = (blockIdx.x * blockDim.x + threadIdx.x) >> 6;
    int lane = threadIdx.x & 63;
    if (wid >= n) return;
    int start = row_ptr[wid], end = row_ptr[wid + 1];
    int oct = lane >> 3, l8 = lane & 7;
    float acc[8];
    #pragma unroll
    for (int i = 0; i < 8; ++i) acc[i] = 0.f;
    for (int b = start; b < end; b += 64) {
        int m = end - b; if (m > 64) m = 64;
        int u = 0;
        if (lane < m) u = col[b + lane];
        for (int j = 0; j < m; j += 8) {
            int jj = j + oct;
            int uu = __shfl(u, jj);
            if (jj < m) {
                const uint4 v = *reinterpret_cast<const uint4*>(yb + (size_t)uu * 64 + 8 * l8);
                float f0, f1;
                unpack2(v.x, f0, f1); acc[0] += f0; acc[1] += f1;
                unpack2(v.y, f0, f1); acc[2] += f0; acc[3] += f1;
                unpack2(v.z, f0, f1); acc[4] += f0; acc[5] += f1;
                unpack2(v.w, f0, f1); acc[6] += f0; acc[7] += f1;
            }
        }
    }
    #pragma unroll
    for (int i = 0; i < 8; ++i) {
        acc[i] += __shfl_xor(acc[i], 8);
        acc[i] += __shfl_xor(acc[i], 16);
        acc[i] += __shfl_xor(acc[i], 32);
    }
    if (lane < 5) {  // oct==0, l8 0..4 -> dims l8*8 .. l8*8+7 (40 total)
        float nd = norm_dst[wid];
        const float* bp = b3 + 8 * lane;
        float* op = out + (size_t)wid * 40 + 8 * lane;
        float4 o0, o1;
        o0.x = fmaf(nd, acc[0], bp[0]); o0.y = fmaf(nd, acc[1], bp[1]);
        o0.z = fmaf(nd, acc[2], bp[2]); o0.w = fmaf(nd, acc[3], bp[3]);
        o1.x = fmaf(nd, acc[4], bp[4]); o1.y = fmaf(nd, acc[5], bp[5]);
        o1.z = fmaf(nd, acc[6], bp[6]); o1.w = fmaf(nd, acc[7], bp[7]);
        *reinterpret_cast<float4*>(op)     = o0;
        *reinterpret_cast<float4*>(op + 4) = o1;
    }
}

extern "C" void kernel_launch(void* const* d_in, const int* in_sizes, int n_in,
                              void* d_out, int out_size, void* d_ws, size_t ws_size,
                              hipStream_t stream) {
    const float* features = (const float*)d_in[0];
    const int*   ei       = (const int*)d_in[1];
    const float* W1 = (const float*)d_in[2];
    const float* b1 = (const float*)d_in[3];
    const float* W2 = (const float*)d_in[4];
    const float* b2 = (const float*)d_in[5];
    const float* W3 = (const float*)d_in[6];
    const float* b3 = (const float*)d_in[7];

    const int n = in_sizes[0] / 128;
    const int E = in_sizes[1] / 2;

    const int nblk1 = (E + EPB - 1) / EPB;      // partition blocks (196)
    const int NB    = (n + 255) >> 8;           // buckets (196)
    const int L     = NB * nblk1;
    const int L2    = 2 * L;                    // D hist + S hist
    const int sb2   = (L2 + SCAN_CHUNK - 1) / SCAN_CHUNK;

    char* w = (char*)d_ws;
    auto alloc = [&](size_t bytes) {
        char* p = w;
        w += (bytes + 255) & ~(size_t)255;
        return p;
    };
    int*    hist_all = (int*)   alloc((size_t)L2 * 4);
    int*    partials = (int*)   alloc((size_t)256 * 4);
    float*  norm_src = (float*) alloc((size_t)n * 4);
    float*  norm_dst = (float*) alloc((size_t)n * 4);
    int*    row_ptr  = (int*)   alloc((size_t)(n + 1) * 4);
    int*    col      = (int*)   alloc((size_t)E * 4);
    ushort* xb       = (ushort*)alloc((size_t)n * 128 * 2);  // bf16 table; yb aliases
    float*  bufA     = (float*) alloc((size_t)n * 128 * 4);  // agg buffer; CSR scratch aliases

    // CSR-build scratch aliases bufA (consumed by bucket_kernel before agg128 writes bufA).
    char* scr = (char*)bufA;
    ushort*        rankD = (ushort*)scr;                 scr += ((size_t)E * 2 + 255) & ~(size_t)255;
    ushort*        rankS = (ushort*)scr;                 scr += ((size_t)E * 2 + 255) & ~(size_t)255;
    unsigned*      packD = (unsigned*)scr;               scr += ((size_t)E * 4 + 255) & ~(size_t)255;
    unsigned char* srcb  = (unsigned char*)scr;
    ushort* yb = xb;   // yb (n*64 bf16) aliases xb; xb2 consumed by agg128 #2
                       // before mm40_l3 writes yb

    int mb16 = (n + 15) / 16;
    int ab   = (n + 3) / 4;

    hist_rank_kernel<<<nblk1, 256, 0, stream>>>(ei, E, nblk1, NB, hist_all, rankD, rankS);
    scanA_kernel<<<sb2, 256, 0, stream>>>(hist_all, L2, partials);
    scanB_kernel<<<1, 256, 0, stream>>>(partials, sb2);
    scanC_kernel<<<sb2, 256, 0, stream>>>(hist_all, L2, partials);
    scatter_part_kernel<<<nblk1, 256, 0, stream>>>(ei, E, nblk1, NB, hist_all,
                                                   rankD, rankS, packD, srcb);
    bucket_kernel<<<2 * NB, 256, 0, stream>>>(packD, srcb, hist_all, nblk1, NB, n, E,
                                              row_ptr, col, norm_src, norm_dst);
    mm1_kernel<<<mb16, 256, 0, stream>>>(features, W1, norm_src, xb, n);
    agg128_kernel<<<ab, 256, 0, stream>>>(xb, row_ptr, col, bufA, n);
    mm128_l2_kernel<<<mb16, 256, 0, stream>>>(bufA, W2, b1, norm_dst, norm_src, xb, n);
    agg128_kernel<<<ab, 256, 0, stream>>>(xb, row_ptr, col, bufA, n);
    mm40_l3_kernel<<<mb16, 256, 0, stream>>>(bufA, W3, b2, norm_dst, norm_src, yb, n);
    agg40_kernel<<<ab, 256, 0, stream>>>(yb, row_ptr, col, norm_dst, b3, (float*)d_out, n);
}